// Round 1
// baseline (100.619 us; speedup 1.0000x reference)
//
#include <hip/hip_runtime.h>
#include <math.h>

// SineSPE MI355X. B=2 L=1024 H=8 D=64 S=10 R=128.
// 32 GEMMs [1024 x 1280]x[1280 x 128]; A(omega*q) built on the fly in LDS.
// K order: [dh(2)][s(10)][dl(32)] pairs -> per 64-k tile s is constant, d affine.
// 2 dispatches: prep_z (z->bf16 tiles + param tables), spe_gemm (no atomics,
// 1024 blocks = 4 blocks/CU = 16 waves/CU, B-tile register prefetch).

typedef short bf16x8 __attribute__((ext_vector_type(8)));
typedef float f32x16 __attribute__((ext_vector_type(16)));

__device__ __forceinline__ unsigned int rnd_bf16(float x) {
    union { float f; unsigned int u; } v; v.f = x;
    return v.u + 0x8000u;
}
// low short = bf16(c) (even k = cos), high short = bf16(s) (odd k = sin)
__device__ __forceinline__ unsigned int pack_bf16(float c, float s) {
    return __builtin_amdgcn_perm(rnd_bf16(s), rnd_bf16(c), 0x07060302u);
}

// zt tile per (bh, kb=dh*10+s): 16KB = [g(4)][r(128)][c(16)] shorts, kkl=g*16+c=2*dl+cs.
// Also: frof[qk*5120 + h*640 + s*64 + d] = {sigmoid(freq)/2, qk==0 ? off/2pi : 0}
__global__ __launch_bounds__(256) void prep_z(
    const float* __restrict__ freqs, const float* __restrict__ offsets,
    const float* __restrict__ gains, const float* __restrict__ z,
    uint4* __restrict__ zt, float2* __restrict__ frof)
{
    const float scale = 0.011048543456039806f;     // 1/sqrt(R*D)
    int bid = blockIdx.x;                          // bh*20 + kb
    int bh = bid / 20, kb = bid - bh * 20;
    int h = bh & 7;
    int dh = (kb >= 10) ? 1 : 0, s = kb - dh * 10;
    int t = threadIdx.x;

    __shared__ float gsl[64];                      // [dl(32)][parity(2)]

    if (t < 16) {                                  // param tables (5120 total)
        int i = bid * 16 + t;
        int hh = i / 640, rem = i - hh * 640;
        int ss = rem >> 6, dd = rem & 63;
        int src = (hh * 64 + dd) * 10 + ss;
        float fr = 0.5f / (1.0f + __expf(-freqs[src]));
        frof[i] = make_float2(fr, offsets[src] * 0.15915494309189535f);
        frof[5120 + i] = make_float2(fr, 0.0f);
    }
    if (t < 64) {                                  // softplus-gain for this tile
        int dl = t >> 1, par = t & 1;
        int tt = 2 * s + par;
        int jm = (tt < 10) ? tt : tt - 10;
        float gn = gains[(h * 64 + dh * 32 + dl) * 10 + jm];
        gsl[t] = (fmaxf(gn, 0.0f) + log1pf(__expf(-fabsf(gn)))) * scale;
    }
    __syncthreads();

    const float* zb = z + (size_t)bh * 163840;     // [d][tt][r]
    uint4* outb = zt + (size_t)bid * 1024;

    #pragma unroll
    for (int i = 0; i < 4; i++) {
        int e = i * 256 + t;
        int r = (e >> 1) & 127, c8 = e & 1;
        int dl0 = i * 8 + c8 * 4;                  // dl base for this uint4
        unsigned int u[4];
        #pragma unroll
        for (int m = 0; m < 4; m++) {
            int dl = dl0 + m;
            int d = dh * 32 + dl;
            float ve = zb[((size_t)d * 20 + 2 * s) * 128 + r] * gsl[dl * 2];
            float vo = zb[((size_t)d * 20 + 2 * s + 1) * 128 + r] * gsl[dl * 2 + 1];
            u[m] = pack_bf16(ve, vo);
        }
        outb[e] = make_uint4(u[0], u[1], u[2], u[3]);
    }
}

__global__ __launch_bounds__(256, 4) void spe_gemm(
    const float* __restrict__ queries, const float* __restrict__ keys,
    const float2* __restrict__ frof, const unsigned short* __restrict__ zt,
    float* __restrict__ out)
{
    __shared__ unsigned int At[2][1024];   // [buf][row*32 + swz-chunk*4 + j], 8KB

    int bid = blockIdx.x;
    int h = bid & 7;                       // XCD swizzle: same-h -> same XCD
    int u = bid >> 3;
    int qk = u & 1, b = (u >> 1) & 1, lt = u >> 2;   // lt 0..31
    int l0 = lt * 32;

    int t = threadIdx.x, w = t >> 6, lane = t & 63;
    int ml = lane & 31, hi = lane >> 5;
    int arow = t >> 3, pg = t & 7;         // A-build: row 0..31, pair-group 0..7

    const float* qsrc = (qk ? keys : queries)
                      + ((size_t)(b * 1024 + l0 + arow) * 8 + h) * 64 + pg * 4;
    const float2* fob = frof + qk * 5120 + h * 640 + pg * 4;
    const unsigned short* bbase = zt + (size_t)(b * 8 + h) * 163840
                                + (w * 32 + ml) * 16 + hi * 8;
    float lf = (float)(l0 + arow);
    unsigned int awz = arow * 32 + ((pg ^ (arow & 7)) << 2);  // A-write dword idx

    float4 qf = *(const float4*)(qsrc);    // dh=0 q slice

    // ---- prologue: B tile 0 into regs; A tile 0 into buf0 ----
    bf16x8 n0 = *(const bf16x8*)(bbase);
    bf16x8 n1 = *(const bf16x8*)(bbase + 2048);
    bf16x8 n2 = *(const bf16x8*)(bbase + 4096);
    bf16x8 n3 = *(const bf16x8*)(bbase + 6144);
    {
        const float4* fp = (const float4*)(fob);
        float4 fA = fp[0], fB = fp[1];
        float p0 = __builtin_amdgcn_fractf(fmaf(fA.x, lf, fA.y));
        float p1 = __builtin_amdgcn_fractf(fmaf(fA.z, lf, fA.w));
        float p2 = __builtin_amdgcn_fractf(fmaf(fB.x, lf, fB.y));
        float p3 = __builtin_amdgcn_fractf(fmaf(fB.z, lf, fB.w));
        uint4 a4;
        a4.x = pack_bf16(__builtin_amdgcn_cosf(p0) * qf.x, __builtin_amdgcn_sinf(p0) * qf.x);
        a4.y = pack_bf16(__builtin_amdgcn_cosf(p1) * qf.y, __builtin_amdgcn_sinf(p1) * qf.y);
        a4.z = pack_bf16(__builtin_amdgcn_cosf(p2) * qf.z, __builtin_amdgcn_sinf(p2) * qf.z);
        a4.w = pack_bf16(__builtin_amdgcn_cosf(p3) * qf.w, __builtin_amdgcn_sinf(p3) * qf.w);
        *(uint4*)&At[0][awz] = a4;
    }

    f32x16 acc = {};

    #pragma unroll 2
    for (int kb = 0; kb < 20; kb++) {
        __syncthreads();                   // tile kb A-writes visible; old reads done
        int cur = kb & 1;

        // current B tile from prefetch regs
        bf16x8 c0 = n0, c1 = n1, c2 = n2, c3 = n3;

        // issue next B tile loads (in flight under this iter's MFMA block)
        int kn = (kb < 19) ? kb + 1 : 19;  // branchless clamp (kb=19 dup, unused)
        const unsigned short* tp = bbase + (size_t)kn * 8192;
        n0 = *(const bf16x8*)(tp);
        n1 = *(const bf16x8*)(tp + 2048);
        n2 = *(const bf16x8*)(tp + 4096);
        n3 = *(const bf16x8*)(tp + 6144);

        // build A tile kn into the other buffer (kb=19: writes never read)
        {
            int dh = (kn >= 10) ? 1 : 0;
            int s = kn - dh * 10;
            if (kn == 10) qf = *(const float4*)(qsrc + 32);   // dh=1 q slice
            const float4* fp = (const float4*)(fob + s * 64 + dh * 32);
            float4 fA = fp[0], fB = fp[1];
            float p0 = __builtin_amdgcn_fractf(fmaf(fA.x, lf, fA.y));
            float p1 = __builtin_amdgcn_fractf(fmaf(fA.z, lf, fA.w));
            float p2 = __builtin_amdgcn_fractf(fmaf(fB.x, lf, fB.y));
            float p3 = __builtin_amdgcn_fractf(fmaf(fB.z, lf, fB.w));
            uint4 a4;
            a4.x = pack_bf16(__builtin_amdgcn_cosf(p0) * qf.x, __builtin_amdgcn_sinf(p0) * qf.x);
            a4.y = pack_bf16(__builtin_amdgcn_cosf(p1) * qf.y, __builtin_amdgcn_sinf(p1) * qf.y);
            a4.z = pack_bf16(__builtin_amdgcn_cosf(p2) * qf.z, __builtin_amdgcn_sinf(p2) * qf.z);
            a4.w = pack_bf16(__builtin_amdgcn_cosf(p3) * qf.w, __builtin_amdgcn_sinf(p3) * qf.w);
            *(uint4*)&At[cur ^ 1][awz] = a4;
        }

        // MFMA over 4 k-steps; A-frag from swizzled LDS (conflict-free b128)
        #pragma unroll
        for (int ks = 0; ks < 4; ks++) {
            bf16x8 a = *(const bf16x8*)&At[cur][ml * 32 + (((ks * 2 + hi) ^ (ml & 7)) << 2)];
            bf16x8 bb = (ks == 0) ? c0 : (ks == 1) ? c1 : (ks == 2) ? c2 : c3;
            acc = __builtin_amdgcn_mfma_f32_32x32x16_bf16(a, bb, acc, 0, 0, 0);
        }
    }

    // ---- epilogue: each element stored once. C/D: col=lane&31, row=(reg&3)+8*(reg>>2)+4*hi
    float* ob = out + (size_t)qk * 2097152 + (size_t)b * 1048576
              + (size_t)h * 128 + w * 32 + ml;
    #pragma unroll
    for (int reg = 0; reg < 16; reg++) {
        int row = l0 + (reg & 3) + 8 * (reg >> 2) + 4 * hi;
        ob[(size_t)row * 1024] = acc[reg];
    }
}

extern "C" void kernel_launch(void* const* d_in, const int* in_sizes, int n_in,
                              void* d_out, int out_size, void* d_ws, size_t ws_size,
                              hipStream_t stream) {
    const float* queries = (const float*)d_in[0];
    const float* keys    = (const float*)d_in[1];
    const float* freqs   = (const float*)d_in[2];
    const float* offsets = (const float*)d_in[3];
    const float* gains   = (const float*)d_in[4];
    const float* z       = (const float*)d_in[5];
    float* out = (float*)d_out;

    float2* frof = (float2*)d_ws;                          // 10240 float2 = 80KB
    uint4* zt = (uint4*)((char*)d_ws + 81920);             // 5.24MB bf16 tiles

    prep_z<<<320, 256, 0, stream>>>(freqs, offsets, gains, z, zt, frof);
    spe_gemm<<<1024, 256, 0, stream>>>(queries, keys, frof,
                                       (const unsigned short*)zt, out);
}

// Round 2
// 99.244 us; speedup vs baseline: 1.0139x; 1.0139x over previous
//
#include <hip/hip_runtime.h>
#include <math.h>

// SineSPE MI355X. B=2 L=1024 H=8 D=64 S=10 R=128.
// qk-FUSED: 16 block-groups of [1024 x 1280]x[1280 x 128] computing BOTH qhat
// and khat per block (B matrix zt is identical for q and k; only A differs:
// phase_q = fract(fr*l + off), phase_k = fract(fr*l)). Halves B L2 traffic.
// 512 blocks = 2 blocks/CU = 8 waves/CU; B-tile register prefetch 1 ahead.

typedef short bf16x8 __attribute__((ext_vector_type(8)));
typedef float f32x16 __attribute__((ext_vector_type(16)));

__device__ __forceinline__ unsigned int rnd_bf16(float x) {
    union { float f; unsigned int u; } v; v.f = x;
    return v.u + 0x8000u;
}
// low short = bf16(c) (even k = cos), high short = bf16(s) (odd k = sin)
__device__ __forceinline__ unsigned int pack_bf16(float c, float s) {
    return __builtin_amdgcn_perm(rnd_bf16(s), rnd_bf16(c), 0x07060302u);
}

// zt tile per (bh, kb=dh*10+s): 16KB = [g(4)][r(128)][c(16)] shorts, kkl=g*16+c=2*dl+cs.
// frof[h*640 + s*64 + d] = {sigmoid(freq)/2, off/2pi}   (single table; k uses off=0)
__global__ __launch_bounds__(256) void prep_z(
    const float* __restrict__ freqs, const float* __restrict__ offsets,
    const float* __restrict__ gains, const float* __restrict__ z,
    uint4* __restrict__ zt, float2* __restrict__ frof)
{
    const float scale = 0.011048543456039806f;     // 1/sqrt(R*D)
    int bid = blockIdx.x;                          // bh*20 + kb
    int bh = bid / 20, kb = bid - bh * 20;
    int h = bh & 7;
    int dh = (kb >= 10) ? 1 : 0, s = kb - dh * 10;
    int t = threadIdx.x;

    __shared__ float gsl[64];                      // [dl(32)][parity(2)]

    if (t < 16) {                                  // param table (5120 total)
        int i = bid * 16 + t;
        int hh = i / 640, rem = i - hh * 640;
        int ss = rem >> 6, dd = rem & 63;
        int src = (hh * 64 + dd) * 10 + ss;
        float fr = 0.5f / (1.0f + __expf(-freqs[src]));
        frof[i] = make_float2(fr, offsets[src] * 0.15915494309189535f);
    }
    if (t < 64) {                                  // softplus-gain for this tile
        int dl = t >> 1, par = t & 1;
        int tt = 2 * s + par;
        int jm = (tt < 10) ? tt : tt - 10;
        float gn = gains[(h * 64 + dh * 32 + dl) * 10 + jm];
        gsl[t] = (fmaxf(gn, 0.0f) + log1pf(__expf(-fabsf(gn)))) * scale;
    }
    __syncthreads();

    const float* zb = z + (size_t)bh * 163840;     // [d][tt][r]
    uint4* outb = zt + (size_t)bid * 1024;

    #pragma unroll
    for (int i = 0; i < 4; i++) {
        int e = i * 256 + t;
        int r = (e >> 1) & 127, c8 = e & 1;
        int dl0 = i * 8 + c8 * 4;                  // dl base for this uint4
        unsigned int u[4];
        #pragma unroll
        for (int m = 0; m < 4; m++) {
            int dl = dl0 + m;
            int d = dh * 32 + dl;
            float ve = zb[((size_t)d * 20 + 2 * s) * 128 + r] * gsl[dl * 2];
            float vo = zb[((size_t)d * 20 + 2 * s + 1) * 128 + r] * gsl[dl * 2 + 1];
            u[m] = pack_bf16(ve, vo);
        }
        outb[e] = make_uint4(u[0], u[1], u[2], u[3]);
    }
}

__global__ __launch_bounds__(256, 2) void spe_gemm(
    const float* __restrict__ queries, const float* __restrict__ keys,
    const float2* __restrict__ frof, const unsigned short* __restrict__ zt,
    float* __restrict__ out)
{
    __shared__ unsigned int At[2][2][1024];  // [qk][buf][row*32 + swz-chunk*4 + j], 32KB

    int bid = blockIdx.x;
    int h = bid & 7;                       // XCD swizzle: same-h -> same XCD
    int u = bid >> 3;
    int b = u & 1, lt = u >> 1;            // lt 0..31
    int l0 = lt * 32;

    int t = threadIdx.x, w = t >> 6, lane = t & 63;
    int ml = lane & 31, hi = lane >> 5;
    int arow = t >> 3, pg = t & 7;         // A-build: row 0..31, pair-group 0..7

    const float* qsrc = queries + ((size_t)(b * 1024 + l0 + arow) * 8 + h) * 64 + pg * 4;
    const float* ksrc = keys    + ((size_t)(b * 1024 + l0 + arow) * 8 + h) * 64 + pg * 4;
    const float2* fob = frof + h * 640 + pg * 4;
    const unsigned short* bbase = zt + (size_t)(b * 8 + h) * 163840
                                + (w * 32 + ml) * 16 + hi * 8;
    float lf = (float)(l0 + arow);
    unsigned int awz = arow * 32 + ((pg ^ (arow & 7)) << 2);  // A-write dword idx

    float4 qf = *(const float4*)(qsrc);    // dh=0 slices
    float4 kf = *(const float4*)(ksrc);

    // ---- prologue: B tile 0 into regs; A tiles 0 into buf0 ----
    bf16x8 n0 = *(const bf16x8*)(bbase);
    bf16x8 n1 = *(const bf16x8*)(bbase + 2048);
    bf16x8 n2 = *(const bf16x8*)(bbase + 4096);
    bf16x8 n3 = *(const bf16x8*)(bbase + 6144);
    {
        const float4* fp = (const float4*)(fob);
        float4 fA = fp[0], fB = fp[1];
        float a0 = fA.x * lf, a1 = fA.z * lf, a2 = fB.x * lf, a3 = fB.z * lf;
        float pq0 = __builtin_amdgcn_fractf(a0 + fA.y);
        float pq1 = __builtin_amdgcn_fractf(a1 + fA.w);
        float pq2 = __builtin_amdgcn_fractf(a2 + fB.y);
        float pq3 = __builtin_amdgcn_fractf(a3 + fB.w);
        float pk0 = __builtin_amdgcn_fractf(a0);
        float pk1 = __builtin_amdgcn_fractf(a1);
        float pk2 = __builtin_amdgcn_fractf(a2);
        float pk3 = __builtin_amdgcn_fractf(a3);
        uint4 aq, ak;
        aq.x = pack_bf16(__builtin_amdgcn_cosf(pq0) * qf.x, __builtin_amdgcn_sinf(pq0) * qf.x);
        aq.y = pack_bf16(__builtin_amdgcn_cosf(pq1) * qf.y, __builtin_amdgcn_sinf(pq1) * qf.y);
        aq.z = pack_bf16(__builtin_amdgcn_cosf(pq2) * qf.z, __builtin_amdgcn_sinf(pq2) * qf.z);
        aq.w = pack_bf16(__builtin_amdgcn_cosf(pq3) * qf.w, __builtin_amdgcn_sinf(pq3) * qf.w);
        ak.x = pack_bf16(__builtin_amdgcn_cosf(pk0) * kf.x, __builtin_amdgcn_sinf(pk0) * kf.x);
        ak.y = pack_bf16(__builtin_amdgcn_cosf(pk1) * kf.y, __builtin_amdgcn_sinf(pk1) * kf.y);
        ak.z = pack_bf16(__builtin_amdgcn_cosf(pk2) * kf.z, __builtin_amdgcn_sinf(pk2) * kf.z);
        ak.w = pack_bf16(__builtin_amdgcn_cosf(pk3) * kf.w, __builtin_amdgcn_sinf(pk3) * kf.w);
        *(uint4*)&At[0][0][awz] = aq;
        *(uint4*)&At[1][0][awz] = ak;
    }

    f32x16 accq = {};
    f32x16 acck = {};

    #pragma unroll 2
    for (int kb = 0; kb < 20; kb++) {
        __syncthreads();                   // tile kb A-writes visible; old reads done
        int cur = kb & 1;

        // current B tile from prefetch regs
        bf16x8 c0 = n0, c1 = n1, c2 = n2, c3 = n3;

        // issue next B tile loads (in flight under this iter's MFMA block)
        int kn = (kb < 19) ? kb + 1 : 19;  // branchless clamp (kb=19 dup, unused)
        const unsigned short* tp = bbase + (size_t)kn * 8192;
        n0 = *(const bf16x8*)(tp);
        n1 = *(const bf16x8*)(tp + 2048);
        n2 = *(const bf16x8*)(tp + 4096);
        n3 = *(const bf16x8*)(tp + 6144);

        // build A tiles kn into the other buffer (kb=19: writes never read)
        {
            int dh = (kn >= 10) ? 1 : 0;
            int s = kn - dh * 10;
            if (kn == 10) {                // dh=1 slices
                qf = *(const float4*)(qsrc + 32);
                kf = *(const float4*)(ksrc + 32);
            }
            const float4* fp = (const float4*)(fob + s * 64 + dh * 32);
            float4 fA = fp[0], fB = fp[1];
            float a0 = fA.x * lf, a1 = fA.z * lf, a2 = fB.x * lf, a3 = fB.z * lf;
            float pq0 = __builtin_amdgcn_fractf(a0 + fA.y);
            float pq1 = __builtin_amdgcn_fractf(a1 + fA.w);
            float pq2 = __builtin_amdgcn_fractf(a2 + fB.y);
            float pq3 = __builtin_amdgcn_fractf(a3 + fB.w);
            float pk0 = __builtin_amdgcn_fractf(a0);
            float pk1 = __builtin_amdgcn_fractf(a1);
            float pk2 = __builtin_amdgcn_fractf(a2);
            float pk3 = __builtin_amdgcn_fractf(a3);
            uint4 aq, ak;
            aq.x = pack_bf16(__builtin_amdgcn_cosf(pq0) * qf.x, __builtin_amdgcn_sinf(pq0) * qf.x);
            aq.y = pack_bf16(__builtin_amdgcn_cosf(pq1) * qf.y, __builtin_amdgcn_sinf(pq1) * qf.y);
            aq.z = pack_bf16(__builtin_amdgcn_cosf(pq2) * qf.z, __builtin_amdgcn_sinf(pq2) * qf.z);
            aq.w = pack_bf16(__builtin_amdgcn_cosf(pq3) * qf.w, __builtin_amdgcn_sinf(pq3) * qf.w);
            ak.x = pack_bf16(__builtin_amdgcn_cosf(pk0) * kf.x, __builtin_amdgcn_sinf(pk0) * kf.x);
            ak.y = pack_bf16(__builtin_amdgcn_cosf(pk1) * kf.y, __builtin_amdgcn_sinf(pk1) * kf.y);
            ak.z = pack_bf16(__builtin_amdgcn_cosf(pk2) * kf.z, __builtin_amdgcn_sinf(pk2) * kf.z);
            ak.w = pack_bf16(__builtin_amdgcn_cosf(pk3) * kf.w, __builtin_amdgcn_sinf(pk3) * kf.w);
            *(uint4*)&At[0][cur ^ 1][awz] = aq;
            *(uint4*)&At[1][cur ^ 1][awz] = ak;
        }

        // MFMA over 4 k-steps; A-frags from swizzled LDS (conflict-free b128)
        #pragma unroll
        for (int ks = 0; ks < 4; ks++) {
            unsigned int off = ml * 32 + (((ks * 2 + hi) ^ (ml & 7)) << 2);
            bf16x8 aq = *(const bf16x8*)&At[0][cur][off];
            bf16x8 ak = *(const bf16x8*)&At[1][cur][off];
            bf16x8 bb = (ks == 0) ? c0 : (ks == 1) ? c1 : (ks == 2) ? c2 : c3;
            accq = __builtin_amdgcn_mfma_f32_32x32x16_bf16(aq, bb, accq, 0, 0, 0);
            acck = __builtin_amdgcn_mfma_f32_32x32x16_bf16(ak, bb, acck, 0, 0, 0);
        }
    }

    // ---- epilogue: C/D: col=lane&31, row=(reg&3)+8*(reg>>2)+4*hi
    float* obq = out + (size_t)b * 1048576 + (size_t)h * 128 + w * 32 + ml;
    float* obk = obq + 2097152;
    #pragma unroll
    for (int reg = 0; reg < 16; reg++) {
        int row = l0 + (reg & 3) + 8 * (reg >> 2) + 4 * hi;
        obq[(size_t)row * 1024] = accq[reg];
        obk[(size_t)row * 1024] = acck[reg];
    }
}

extern "C" void kernel_launch(void* const* d_in, const int* in_sizes, int n_in,
                              void* d_out, int out_size, void* d_ws, size_t ws_size,
                              hipStream_t stream) {
    const float* queries = (const float*)d_in[0];
    const float* keys    = (const float*)d_in[1];
    const float* freqs   = (const float*)d_in[2];
    const float* offsets = (const float*)d_in[3];
    const float* gains   = (const float*)d_in[4];
    const float* z       = (const float*)d_in[5];
    float* out = (float*)d_out;

    float2* frof = (float2*)d_ws;                          // 5120 float2 = 40KB
    uint4* zt = (uint4*)((char*)d_ws + 81920);             // 5.24MB bf16 tiles

    prep_z<<<320, 256, 0, stream>>>(freqs, offsets, gains, z, zt, frof);
    spe_gemm<<<512, 256, 0, stream>>>(queries, keys, frof,
                                      (const unsigned short*)zt, out);
}